// Round 1
// baseline (406.784 us; speedup 1.0000x reference)
//
#include <hip/hip_runtime.h>
#include <stddef.h>
#include <stdint.h>

// ---------- problem dims (fixed by setup_inputs) ----------
#define BDIM 2
#define SDIM 2048
#define DDIM 1024
#define FDIM 4096
#define ENUM 8
#define KSEL 2
#define TTOK (BDIM * SDIM)        // 4096 tokens
#define PPAIR (TTOK * KSEL)       // 8192 (token,k) pairs
#define VOUT ((size_t)TTOK * DDIM) // 4194304 floats of "mixed"

typedef float f32x4 __attribute__((ext_vector_type(4)));
typedef short bf16x8 __attribute__((ext_vector_type(8)));
typedef unsigned short u16x8 __attribute__((ext_vector_type(8)));
typedef unsigned short u16x4 __attribute__((ext_vector_type(4)));

__device__ __forceinline__ unsigned short f2bf(float f) {
  unsigned int u = __float_as_uint(f);
  u += 0x7fffu + ((u >> 16) & 1u);   // RNE
  return (unsigned short)(u >> 16);
}

__device__ __forceinline__ float gelu_tanh(float x) {
  // jax.nn.gelu(approximate=True): 0.5x(1+tanh(0.79788456(x+0.044715x^3)))
  float u = 0.7978845608028654f * (x + 0.044715f * x * x * x);
  float e = __expf(2.0f * u);
  float t = 1.0f - 2.0f / (e + 1.0f);   // tanh(u), safe at +-inf
  return 0.5f * x * (1.0f + t);
}

__device__ __forceinline__ void gload16(const void* g, void* l) {
  __builtin_amdgcn_global_load_lds(
      (const __attribute__((address_space(1))) unsigned int*)g,
      (__attribute__((address_space(3))) unsigned int*)l, 16, 0, 0);
}

// ---------- kernel 1: router stats (entropy mean, winner margin mean) ----------
__global__ __launch_bounds__(256) void stats_kernel(const float* __restrict__ lg,
                                                    float* __restrict__ out) {
  __shared__ float se[256], sm[256];
  float ent = 0.f, mar = 0.f;
  for (int r = threadIdx.x; r < TTOK; r += 256) {
    float v[ENUM];
    float mx = -1e30f;
#pragma unroll
    for (int i = 0; i < ENUM; ++i) { v[i] = lg[r * ENUM + i]; mx = fmaxf(mx, v[i]); }
    float s = 0.f;
#pragma unroll
    for (int i = 0; i < ENUM; ++i) { v[i] = __expf(v[i] - mx); s += v[i]; }
    float inv = 1.f / s;
    float p1 = -1.f, p2 = -1.f, e_ = 0.f;
#pragma unroll
    for (int i = 0; i < ENUM; ++i) {
      float p = v[i] * inv;
      e_ -= p * logf(fmaxf(p, 1e-9f));
      if (p > p1) { p2 = p1; p1 = p; } else if (p > p2) { p2 = p; }
    }
    ent += e_; mar += (p1 - p2);
  }
  se[threadIdx.x] = ent; sm[threadIdx.x] = mar;
  __syncthreads();
  for (int s = 128; s > 0; s >>= 1) {
    if (threadIdx.x < (unsigned)s) { se[threadIdx.x] += se[threadIdx.x + s]; sm[threadIdx.x] += sm[threadIdx.x + s]; }
    __syncthreads();
  }
  if (threadIdx.x == 0) {
    out[VOUT]     = se[0] / (float)TTOK;
    out[VOUT + 1] = sm[0] / (float)TTOK;
  }
}

// ---------- kernel 2: routing (group pairs by expert) ----------
__global__ __launch_bounds__(256) void routing_kernel(const int* __restrict__ eidx,
                                                      int* __restrict__ g_cnt,
                                                      int* __restrict__ g_off,
                                                      int* __restrict__ pairTok,
                                                      int* __restrict__ pairDst) {
  __shared__ int sc[ENUM], so[ENUM], scur[ENUM];
  const int tid = threadIdx.x;
  if (tid < ENUM) sc[tid] = 0;
  __syncthreads();
  for (int p = tid; p < PPAIR; p += 256) atomicAdd(&sc[eidx[p]], 1);
  __syncthreads();
  if (tid == 0) { int o = 0; for (int e = 0; e < ENUM; ++e) { so[e] = o; o += sc[e]; } }
  __syncthreads();
  if (tid < ENUM) { scur[tid] = so[tid]; g_cnt[tid] = sc[tid]; g_off[tid] = so[tid]; }
  __syncthreads();
  for (int p = tid; p < PPAIR; p += 256) {
    int e = eidx[p];
    int pos = atomicAdd(&scur[e], 1);
    pairTok[pos] = p >> 1;  // token id
    pairDst[pos] = p;       // dest row = token*K + k
  }
}

// ---------- kernel 3: hidden fp32 -> bf16 ----------
__global__ __launch_bounds__(256) void cvt_hidden_kernel(const float* __restrict__ in,
                                                         unsigned short* __restrict__ outp) {
  const int i = blockIdx.x * 256 + threadIdx.x;  // covers TTOK*DDIM/8 = 524288
  f32x4 a = ((const f32x4*)in)[(size_t)i * 2];
  f32x4 b = ((const f32x4*)in)[(size_t)i * 2 + 1];
  u16x8 o;
  o[0] = f2bf(a[0]); o[1] = f2bf(a[1]); o[2] = f2bf(a[2]); o[3] = f2bf(a[3]);
  o[4] = f2bf(b[0]); o[5] = f2bf(b[1]); o[6] = f2bf(b[2]); o[7] = f2bf(b[3]);
  ((u16x8*)outp)[i] = o;
}

// ---------- kernel 4: transpose + convert: in fp32 [R][C] -> out bf16 [C][R] (per expert z) ----------
__global__ __launch_bounds__(256) void transpose_cvt_kernel(const float* __restrict__ in,
                                                            unsigned short* __restrict__ outp,
                                                            int R, int C) {
  __shared__ float tile[32][33];
  const size_t base = (size_t)blockIdx.z * (size_t)R * (size_t)C;
  const float* ip = in + base;
  unsigned short* op = outp + base;
  const int r0 = blockIdx.y * 32, c0 = blockIdx.x * 32;
  const int i = threadIdx.x >> 3;
  const int j4 = (threadIdx.x & 7) << 2;
  f32x4 v = *(const f32x4*)(ip + (size_t)(r0 + i) * C + c0 + j4);
  tile[i][j4 + 0] = v[0]; tile[i][j4 + 1] = v[1]; tile[i][j4 + 2] = v[2]; tile[i][j4 + 3] = v[3];
  __syncthreads();
  u16x4 o;
  o[0] = f2bf(tile[j4 + 0][i]); o[1] = f2bf(tile[j4 + 1][i]);
  o[2] = f2bf(tile[j4 + 2][i]); o[3] = f2bf(tile[j4 + 3][i]);
  *(u16x4*)(op + (size_t)(c0 + i) * R + r0 + j4) = o;
}

// ---------- grouped GEMM 1: h1 = gelu(hB[tok] @ w1T[e]^T + b1[e])  (bf16 out, grouped rows) ----------
__global__ __launch_bounds__(256) void gemm1_kernel(const unsigned short* __restrict__ hB,   // [T][D]
                                                    const unsigned short* __restrict__ w1T,  // [E][F][D]
                                                    const float* __restrict__ b1,            // [E][F]
                                                    const int* __restrict__ g_cnt,
                                                    const int* __restrict__ g_off,
                                                    const int* __restrict__ pairTok,
                                                    unsigned short* __restrict__ h1) {       // [P][F]
  const int e = blockIdx.z;
  const int cnt_e = g_cnt[e];
  const int m0 = blockIdx.y << 7;
  if (m0 >= cnt_e) return;
  const int off_e = g_off[e];
  const int rows_e = min(128, cnt_e - m0);
  const int n0 = blockIdx.x << 7;

  __shared__ __align__(16) unsigned short As[2][128 * 32];
  __shared__ __align__(16) unsigned short Bs[2][128 * 32];

  const int tid = threadIdx.x;
  const int lane = tid & 63;
  const int wid = tid >> 6;
  const int wr = wid >> 1, wc = wid & 1;

  // staging: per wave 2 A-regions + 2 B-regions of 1KB (16 rows x 32 k bf16)
  // pre-swizzled global slot so that linear global_load_lds dest matches the
  // swizzled read layout (both-sides-or-neither)
  const int l2 = lane >> 2;
  const int sg = (lane & 3) ^ ((lane >> 3) & 3);
  const unsigned short* gA[2];
  const unsigned short* gB[2];
  int ldsOff[2];
#pragma unroll
  for (int c = 0; c < 2; ++c) {
    const int reg = wid * 2 + c;
    const int row = reg * 16 + l2;
    const int tok = pairTok[off_e + m0 + min(row, rows_e - 1)];
    gA[c] = hB + (size_t)tok * DDIM + (sg << 3);
    gB[c] = w1T + ((size_t)e * FDIM + (n0 + row)) * DDIM + (sg << 3);
    ldsOff[c] = reg * 512;
  }

  const int kh = lane >> 4;
  const int l15 = lane & 15;
  int aoff[4], boff[4];
#pragma unroll
  for (int i = 0; i < 4; ++i) {
    const int ar = wr * 64 + i * 16 + l15;
    aoff[i] = ar * 32 + ((kh ^ ((ar >> 1) & 3)) << 3);
    const int br = wc * 64 + i * 16 + l15;
    boff[i] = br * 32 + ((kh ^ ((br >> 1) & 3)) << 3);
  }

  f32x4 acc[4][4];
#pragma unroll
  for (int i = 0; i < 4; ++i)
#pragma unroll
    for (int j = 0; j < 4; ++j) acc[i][j] = (f32x4){0.f, 0.f, 0.f, 0.f};

#pragma unroll
  for (int c = 0; c < 2; ++c) {
    gload16(gA[c], &As[0][ldsOff[c]]);
    gload16(gB[c], &Bs[0][ldsOff[c]]);
  }
  __syncthreads();

  int cur = 0;
  const int KT = DDIM / 32;
  for (int kt = 0; kt < KT; ++kt) {
    if (kt + 1 < KT) {
#pragma unroll
      for (int c = 0; c < 2; ++c) {
        gload16(gA[c] + (size_t)(kt + 1) * 32, &As[cur ^ 1][ldsOff[c]]);
        gload16(gB[c] + (size_t)(kt + 1) * 32, &Bs[cur ^ 1][ldsOff[c]]);
      }
    }
    bf16x8 af[4], bfr[4];
#pragma unroll
    for (int i = 0; i < 4; ++i) af[i] = *(const bf16x8*)&As[cur][aoff[i]];
#pragma unroll
    for (int i = 0; i < 4; ++i) bfr[i] = *(const bf16x8*)&Bs[cur][boff[i]];
#pragma unroll
    for (int im = 0; im < 4; ++im)
#pragma unroll
      for (int in = 0; in < 4; ++in)
        acc[im][in] = __builtin_amdgcn_mfma_f32_16x16x32_bf16(af[im], bfr[in], acc[im][in], 0, 0, 0);
    __syncthreads();
    cur ^= 1;
  }

#pragma unroll
  for (int im = 0; im < 4; ++im) {
#pragma unroll
    for (int j = 0; j < 4; ++j) {
      const int row = wr * 64 + im * 16 + kh * 4 + j;
      if (row < rows_e) {
        unsigned short* dst = h1 + (size_t)(off_e + m0 + row) * FDIM;
#pragma unroll
        for (int in = 0; in < 4; ++in) {
          const int col = n0 + wc * 64 + in * 16 + l15;
          float x = acc[im][in][j] + b1[e * FDIM + col];
          dst[col] = f2bf(gelu_tanh(x));
        }
      }
    }
  }
}

// ---------- grouped GEMM 2: h2[dst] = h1[q] @ w2T[e]^T + b2[e]  (fp32, scatter to dest row) ----------
__global__ __launch_bounds__(256) void gemm2_kernel(const unsigned short* __restrict__ h1,   // [P][F]
                                                    const unsigned short* __restrict__ w2T,  // [E][D][F]
                                                    const float* __restrict__ b2,            // [E][D]
                                                    const int* __restrict__ g_cnt,
                                                    const int* __restrict__ g_off,
                                                    const int* __restrict__ pairDst,
                                                    float* __restrict__ h2) {                // [P][D] by dst
  const int e = blockIdx.z;
  const int cnt_e = g_cnt[e];
  const int m0 = blockIdx.y << 7;
  if (m0 >= cnt_e) return;
  const int off_e = g_off[e];
  const int rows_e = min(128, cnt_e - m0);
  const int n0 = blockIdx.x << 7;

  __shared__ __align__(16) unsigned short As[2][128 * 32];
  __shared__ __align__(16) unsigned short Bs[2][128 * 32];

  const int tid = threadIdx.x;
  const int lane = tid & 63;
  const int wid = tid >> 6;
  const int wr = wid >> 1, wc = wid & 1;

  const int l2 = lane >> 2;
  const int sg = (lane & 3) ^ ((lane >> 3) & 3);
  const unsigned short* gA[2];
  const unsigned short* gB[2];
  int ldsOff[2];
#pragma unroll
  for (int c = 0; c < 2; ++c) {
    const int reg = wid * 2 + c;
    const int row = reg * 16 + l2;
    const int q = off_e + m0 + min(row, rows_e - 1);
    gA[c] = h1 + (size_t)q * FDIM + (sg << 3);
    gB[c] = w2T + ((size_t)e * DDIM + (n0 + row)) * FDIM + (sg << 3);
    ldsOff[c] = reg * 512;
  }

  const int kh = lane >> 4;
  const int l15 = lane & 15;
  int aoff[4], boff[4];
#pragma unroll
  for (int i = 0; i < 4; ++i) {
    const int ar = wr * 64 + i * 16 + l15;
    aoff[i] = ar * 32 + ((kh ^ ((ar >> 1) & 3)) << 3);
    const int br = wc * 64 + i * 16 + l15;
    boff[i] = br * 32 + ((kh ^ ((br >> 1) & 3)) << 3);
  }

  f32x4 acc[4][4];
#pragma unroll
  for (int i = 0; i < 4; ++i)
#pragma unroll
    for (int j = 0; j < 4; ++j) acc[i][j] = (f32x4){0.f, 0.f, 0.f, 0.f};

#pragma unroll
  for (int c = 0; c < 2; ++c) {
    gload16(gA[c], &As[0][ldsOff[c]]);
    gload16(gB[c], &Bs[0][ldsOff[c]]);
  }
  __syncthreads();

  int cur = 0;
  const int KT = FDIM / 32;
  for (int kt = 0; kt < KT; ++kt) {
    if (kt + 1 < KT) {
#pragma unroll
      for (int c = 0; c < 2; ++c) {
        gload16(gA[c] + (size_t)(kt + 1) * 32, &As[cur ^ 1][ldsOff[c]]);
        gload16(gB[c] + (size_t)(kt + 1) * 32, &Bs[cur ^ 1][ldsOff[c]]);
      }
    }
    bf16x8 af[4], bfr[4];
#pragma unroll
    for (int i = 0; i < 4; ++i) af[i] = *(const bf16x8*)&As[cur][aoff[i]];
#pragma unroll
    for (int i = 0; i < 4; ++i) bfr[i] = *(const bf16x8*)&Bs[cur][boff[i]];
#pragma unroll
    for (int im = 0; im < 4; ++im)
#pragma unroll
      for (int in = 0; in < 4; ++in)
        acc[im][in] = __builtin_amdgcn_mfma_f32_16x16x32_bf16(af[im], bfr[in], acc[im][in], 0, 0, 0);
    __syncthreads();
    cur ^= 1;
  }

#pragma unroll
  for (int im = 0; im < 4; ++im) {
#pragma unroll
    for (int j = 0; j < 4; ++j) {
      const int row = wr * 64 + im * 16 + kh * 4 + j;
      if (row < rows_e) {
        const int q = off_e + m0 + row;
        float* dp = h2 + (size_t)pairDst[q] * DDIM;
#pragma unroll
        for (int in = 0; in < 4; ++in) {
          const int col = n0 + wc * 64 + in * 16 + l15;
          dp[col] = acc[im][in][j] + b2[e * DDIM + col];
        }
      }
    }
  }
}

// ---------- combine: out[t] = w0*h2[2t] + w1*h2[2t+1] ----------
__global__ __launch_bounds__(256) void combine_kernel(const float* __restrict__ h2,
                                                      const float* __restrict__ ew,
                                                      float* __restrict__ out) {
  const int i = blockIdx.x * 256 + threadIdx.x;  // over TTOK*DDIM/4 = 1048576
  const int t = i >> 8;
  const int c = i & 255;
  const float wa = ew[t * 2], wb = ew[t * 2 + 1];
  const f32x4 a = ((const f32x4*)h2)[(size_t)t * 512 + c];
  const f32x4 b = ((const f32x4*)h2)[(size_t)t * 512 + 256 + c];
  f32x4 r = a * wa + b * wb;
  ((f32x4*)out)[i] = r;
}

// ---------- launch ----------
extern "C" void kernel_launch(void* const* d_in, const int* in_sizes, int n_in,
                              void* d_out, int out_size, void* d_ws, size_t ws_size,
                              hipStream_t stream) {
  (void)in_sizes; (void)n_in; (void)out_size; (void)ws_size;
  const float* hidden = (const float*)d_in[0];
  const int*   eidx   = (const int*)d_in[1];
  const float* ew     = (const float*)d_in[2];
  const float* rlog   = (const float*)d_in[3];
  const float* w1     = (const float*)d_in[4];
  const float* b1     = (const float*)d_in[5];
  const float* w2     = (const float*)d_in[6];
  const float* b2     = (const float*)d_in[7];
  float* out = (float*)d_out;

  char* wsb = (char*)d_ws;
  const size_t SZ_W = (size_t)ENUM * DDIM * FDIM * 2;  // 67108864 bytes (bf16)
  unsigned short* w1T = (unsigned short*)(wsb);
  unsigned short* w2T = (unsigned short*)(wsb + SZ_W);
  unsigned short* hB  = (unsigned short*)(wsb + 2 * SZ_W);
  unsigned short* h1  = (unsigned short*)(wsb + 2 * SZ_W + (size_t)TTOK * DDIM * 2);
  int* g_cnt   = (int*)(wsb + 2 * SZ_W + (size_t)TTOK * DDIM * 2 + (size_t)PPAIR * FDIM * 2);
  int* g_off   = g_cnt + 8;
  int* pairTok = g_off + 8;
  int* pairDst = pairTok + PPAIR;
  float* h2 = (float*)wsb;  // aliases w1T (dead after gemm1); 33.5MB <= 64MB

  stats_kernel<<<1, 256, 0, stream>>>(rlog, out);
  routing_kernel<<<1, 256, 0, stream>>>(eidx, g_cnt, g_off, pairTok, pairDst);
  cvt_hidden_kernel<<<(TTOK * DDIM / 8 + 255) / 256, 256, 0, stream>>>(hidden, hB);
  // w1 [E][D][F] -> w1T [E][F][D]
  transpose_cvt_kernel<<<dim3(FDIM / 32, DDIM / 32, ENUM), 256, 0, stream>>>(w1, w1T, DDIM, FDIM);
  // w2 [E][F][D] -> w2T [E][D][F]
  transpose_cvt_kernel<<<dim3(DDIM / 32, FDIM / 32, ENUM), 256, 0, stream>>>(w2, w2T, FDIM, DDIM);
  gemm1_kernel<<<dim3(FDIM / 128, PPAIR / 128, ENUM), 256, 0, stream>>>(hB, w1T, b1, g_cnt, g_off, pairTok, h1);
  gemm2_kernel<<<dim3(DDIM / 128, PPAIR / 128, ENUM), 256, 0, stream>>>(h1, w2T, b2, g_cnt, g_off, pairDst, h2);
  combine_kernel<<<(TTOK * DDIM / 4) / 256, 256, 0, stream>>>(h2, ew, out);
}